// Round 1
// baseline (292.296 us; speedup 1.0000x reference)
//
#include <hip/hip_runtime.h>

// Max-Feature-Map: out[b,k,h,w] = max(x[b,2k,h,w], x[b,2k+1,h,w])
// x: (32,128,112,112) fp32 -> out: (32,64,112,112) fp32.
//
// Pure streaming, 308 MB total, zero reuse -> memory floor ~48 us at 6.4 TB/s.
// This version removes ALL address arithmetic from the hot path and maximizes
// per-thread memory-level parallelism:
//   - 2D-free decomposition: one block per OUTPUT PLANE (2048 blocks).
//     Input planes for output plane p are exactly 2p and 2p+1 (contiguous),
//     so no integer division is needed anywhere.
//   - Plane = 3136 f32x4. Block = 448 threads (7 waves) x 7 f32x4/thread
//     = 3136 exactly. Each thread issues all 14 non-temporal loads up front
//     (14-deep MLP), then 7 maxes + 7 NT stores.
//   - NT flags kept: the harness's 822 MB poison fill between iterations
//     thrashes the 256 MiB L3, so there is no cross-iteration residency to
//     preserve; NT avoids wasting replacement state.

typedef float f32x4 __attribute__((ext_vector_type(4)));

static constexpr int P4 = (112 * 112) / 4;   // 3136 f32x4 per plane
static constexpr int NPLANES_OUT = 32 * 64;  // 2048 output planes
static constexpr int BLOCK = 448;            // 7 waves; 3136 / 448 = 7 exactly
static constexpr int ITERS = P4 / BLOCK;     // 7

__global__ __launch_bounds__(BLOCK) void mfm_kernel(const f32x4* __restrict__ x,
                                                    f32x4* __restrict__ out) {
    const int p = blockIdx.x;        // output plane 0..2047
    const int t = threadIdx.x;       // 0..447

    const f32x4* __restrict__ a = x + (size_t)(2 * p) * P4;  // input plane 2p
    const f32x4* __restrict__ b = a + P4;                    // input plane 2p+1
    f32x4* __restrict__ o = out + (size_t)p * P4;

    f32x4 va[ITERS], vb[ITERS];
#pragma unroll
    for (int k = 0; k < ITERS; ++k)
        va[k] = __builtin_nontemporal_load(&a[t + BLOCK * k]);
#pragma unroll
    for (int k = 0; k < ITERS; ++k)
        vb[k] = __builtin_nontemporal_load(&b[t + BLOCK * k]);
#pragma unroll
    for (int k = 0; k < ITERS; ++k) {
        f32x4 r;
        r.x = fmaxf(va[k].x, vb[k].x);
        r.y = fmaxf(va[k].y, vb[k].y);
        r.z = fmaxf(va[k].z, vb[k].z);
        r.w = fmaxf(va[k].w, vb[k].w);
        __builtin_nontemporal_store(r, &o[t + BLOCK * k]);
    }
}

extern "C" void kernel_launch(void* const* d_in, const int* in_sizes, int n_in,
                              void* d_out, int out_size, void* d_ws, size_t ws_size,
                              hipStream_t stream) {
    const f32x4* x = (const f32x4*)d_in[0];
    f32x4* out = (f32x4*)d_out;
    mfm_kernel<<<NPLANES_OUT, BLOCK, 0, stream>>>(x, out);
}